// Round 1
// baseline (204.303 us; speedup 1.0000x reference)
//
#include <hip/hip_runtime.h>
#include <hip/hip_bf16.h>
#include <stdint.h>

typedef unsigned short u16;
typedef u16 u16x8 __attribute__((ext_vector_type(8)));
typedef u16 u16x4 __attribute__((ext_vector_type(4)));
typedef __bf16 bf16x8 __attribute__((ext_vector_type(8)));
typedef float f32x4 __attribute__((ext_vector_type(4)));

#define MFMA16(a, b, c) __builtin_amdgcn_mfma_f32_16x16x32_bf16((a), (b), (c), 0, 0, 0)

#define SCALE_Q 0.18033688011112042f   /* d^-0.5 (=0.125) * log2(e) */

__device__ __forceinline__ u16 f2b(float f) {   // fp32 -> bf16 rne (4 ops)
    union { float f; unsigned u; } v; v.f = f;
    unsigned r = v.u + 0x7FFFu + ((v.u >> 16) & 1u);
    return (u16)(r >> 16);
}
__device__ __forceinline__ u16 f2b_h(float f) { // fp32 -> bf16 half-up (2 ops)
    union { float f; unsigned u; } v; v.f = f;
    return (u16)((v.u + 0x8000u) >> 16);
}

// ---------------------------------------------------------------------------
// Kernel 0: prep.  Blocks 0..383: W fp32->bf16 (wb[3][512 o][512 c]).
// Blocks 384..1407: x transpose+convert -> xT bf16 [16 b][1024 n][512 c]
// via a [64 c][128 n] LDS tile (coalesced reads, b128 LDS I/O, b128 stores).
// xT lives in d_out (dead before attn overwrites it).
// ---------------------------------------------------------------------------
__global__ __launch_bounds__(256) void prep(
    const float* __restrict__ x,
    const float* __restrict__ Wq, const float* __restrict__ Wk,
    const float* __restrict__ Wv,
    u16* __restrict__ wb, u16* __restrict__ xT) {
    __shared__ __align__(16) u16 Ls[128 * 72];
    const int tid = threadIdx.x;

    if (blockIdx.x < 384) {                       // ---- W convert ----
        int g = blockIdx.x * 256 + tid;           // 98304 chunks of 8
        int which = g >> 15;
        const float* src = which == 0 ? Wq : (which == 1 ? Wk : Wv);
        int off = (g & 32767) * 8;
        f32x4 a = *(const f32x4*)(src + off);
        f32x4 b = *(const f32x4*)(src + off + 4);
        u16x8 o;
#pragma unroll
        for (int i = 0; i < 4; ++i) { o[i] = f2b_h(a[i]); o[4 + i] = f2b_h(b[i]); }
        *(u16x8*)(wb + (size_t)g * 8) = o;
        return;
    }

    // ---- x transpose tile ----
    const int bid = blockIdx.x - 384;             // 0..1023
    const int b  = bid >> 6;                      // 16
    const int ct = (bid >> 3) & 7;                // 8 c-tiles of 64
    const int nt = bid & 7;                       // 8 n-tiles of 128
    const int C0 = ct * 64, N0 = nt * 128;
    const float* xb = x + ((size_t)b << 19);

#pragma unroll
    for (int rep = 0; rep < 4; ++rep) {           // stage-in: [64 c][128 n]
        int id = tid + rep * 256;
        int oct = id >> 7, n = id & 127;          // n lane-consecutive -> coalesced
        const float* xp = xb + (size_t)(C0 + oct * 8) * 1024 + N0 + n;
        u16x8 xv;
#pragma unroll
        for (int k = 0; k < 8; ++k) xv[k] = f2b_h(xp[k * 1024]);
        *(u16x8*)(Ls + n * 72 + oct * 8) = xv;    // transposed [n][c]
    }
    __syncthreads();
#pragma unroll
    for (int rep = 0; rep < 4; ++rep) {           // stage-out: rows of xT
        int id = tid + rep * 256;
        int n = id >> 3, c8 = id & 7;
        *(u16x8*)(xT + ((size_t)b << 19) + (size_t)(N0 + n) * 512 + C0 + c8 * 8) =
            *(u16x8*)(Ls + n * 72 + c8 * 8);
    }
}

// ---------------------------------------------------------------------------
// Kernel 1: QKV projection from pre-converted bf16 xT and wb.
// Staging is pure b128 copies (no cvt), register-prefetched one kt ahead
// (loads fly across the compute phase).  1-D grid, id%8 = n-tile (XCD).
// Epilogue fuses q scale, k += rel table, v transpose.
//   qws/kws: [b*8+h][n][dd] bf16     vws: [b*8+h][dd][n-PERMUTED] bf16
// V n-permutation (within each 32-block, n = 16s+4q+r -> phys 8q+4s+r) makes
// the attn PV B-fragment k-slots line up with the QK^T accumulator layout so
// P never round-trips through LDS (see attn kernel).
// ---------------------------------------------------------------------------
__global__ __launch_bounds__(256, 3) void qkv_proj(
    const u16* __restrict__ xT, const u16* __restrict__ wb,
    const float* __restrict__ bq, const float* __restrict__ bk,
    const float* __restrict__ bv,
    const float* __restrict__ rel_h, const float* __restrict__ rel_w,
    u16* __restrict__ qws, u16* __restrict__ kws, u16* __restrict__ vws) {
    __shared__ __align__(16) u16 Xs[128 * 72];   // [128 n][72]
    __shared__ __align__(16) u16 Ws[128 * 72];   // [128 o][72]

    const int tid  = threadIdx.x;
    const int wave = tid >> 6, lane = tid & 63;
    const int quad = lane >> 4, l16 = lane & 15;
    const int wr = wave >> 1, wc = wave & 1;

    const int id = blockIdx.x;           // 1536 = 8 nt * (4 o0 * 3 mm * 16 b)
    const int nt = id & 7;               // XCD selector
    const int r  = id >> 3;
    const int o0 = r & 3;
    const int r2 = r >> 2;
    const int mm = r2 % 3;
    const int b  = r2 / 3;
    const int N0 = nt * 128;
    const int O0 = o0 * 128;

    const u16*   W    = wb + (size_t)mm * 262144;    // [512 o][512 c]
    const float* bias = mm == 0 ? bq : (mm == 1 ? bk : bv);
    const u16*   Xb   = xT + ((size_t)b << 19);      // [1024 n][512 c]

    const int sr = tid >> 3, sc8 = tid & 7;          // staging row/col-octet

    u16x8 xr[4], wrg[4];
#pragma unroll
    for (int rp = 0; rp < 4; ++rp) {                 // prefetch kt=0
        xr[rp]  = *(const u16x8*)(Xb + (size_t)(N0 + sr + rp * 32) * 512 + sc8 * 8);
        wrg[rp] = *(const u16x8*)(W  + (size_t)(O0 + sr + rp * 32) * 512 + sc8 * 8);
    }

    f32x4 acc[4][4] = {};

    for (int kt = 0; kt < 8; ++kt) {     // K = 512, BK = 64
        __syncthreads();                 // prior frag reads done
#pragma unroll
        for (int rp = 0; rp < 4; ++rp) {
            *(u16x8*)(Xs + (sr + rp * 32) * 72 + sc8 * 8) = xr[rp];
            *(u16x8*)(Ws + (sr + rp * 32) * 72 + sc8 * 8) = wrg[rp];
        }
        __syncthreads();
        if (kt < 7) {
            int c0 = (kt + 1) * 64;
#pragma unroll
            for (int rp = 0; rp < 4; ++rp) {
                xr[rp]  = *(const u16x8*)(Xb + (size_t)(N0 + sr + rp * 32) * 512 + c0 + sc8 * 8);
                wrg[rp] = *(const u16x8*)(W  + (size_t)(O0 + sr + rp * 32) * 512 + c0 + sc8 * 8);
            }
        }
#pragma unroll
        for (int kk = 0; kk < 2; ++kk) {
            bf16x8 af[4], bfr[4];
#pragma unroll
            for (int mi = 0; mi < 4; ++mi)
                af[mi] = *(bf16x8*)(Xs + (wr * 64 + mi * 16 + l16) * 72 + kk * 32 + quad * 8);
#pragma unroll
            for (int ni = 0; ni < 4; ++ni)
                bfr[ni] = *(bf16x8*)(Ws + (wc * 64 + ni * 16 + l16) * 72 + kk * 32 + quad * 8);
#pragma unroll
            for (int mi = 0; mi < 4; ++mi)
#pragma unroll
                for (int ni = 0; ni < 4; ++ni)
                    acc[mi][ni] = MFMA16(af[mi], bfr[ni], acc[mi][ni]);
        }
    }

    // Epilogue. C-layout: col (o-dim) = l16, row (n-dim) = quad*4 + r.
#pragma unroll
    for (int mi = 0; mi < 4; ++mi) {
#pragma unroll
        for (int ni = 0; ni < 4; ++ni) {
            int o  = O0 + wc * 64 + ni * 16 + l16;
            int h  = o >> 6, dd = o & 63;
            size_t bh = (size_t)b * 8 + h;
            float bv_ = bias[o];
            int n0 = N0 + wr * 64 + mi * 16 + quad * 4;
            if (mm == 2) {
                u16x4 pk;
#pragma unroll
                for (int rr = 0; rr < 4; ++rr) pk[rr] = f2b(acc[mi][ni][rr] + bv_);
                // V column permutation: n = ..|16s+4q+r  ->  phys ..|8q+4s+r.
                // n0 has r=0; the 4 stored columns share (s,q).
                int qq = (n0 >> 2) & 3, ss = (n0 >> 4) & 1;
                int np = (n0 & ~31) | (qq * 8 + ss * 4);
                *(u16x4*)(vws + (bh * 64 + dd) * 1024 + np) = pk;
            } else if (mm == 0) {
#pragma unroll
                for (int rr = 0; rr < 4; ++rr)
                    qws[(bh * 1024 + (n0 + rr)) * 64 + dd] =
                        f2b((acc[mi][ni][rr] + bv_) * SCALE_Q);
            } else {
                float th = rel_h[dd * 32 + (n0 >> 5)];
                f32x4 tw = *(const f32x4*)(rel_w + dd * 32 + (n0 & 31));
#pragma unroll
                for (int rr = 0; rr < 4; ++rr)
                    kws[(bh * 1024 + n0 + rr) * 64 + dd] =
                        f2b(acc[mi][ni][rr] + bv_ + th + tw[rr]);
            }
        }
    }
}

// ---------------------------------------------------------------------------
// Kernel 2: flash attention per (b, h, 128-row Q tile); id%8=h XCD swizzle.
// jt-tile 64, register-prefetched staging + DOUBLE-BUFFERED K/V LDS tiles
// (1 barrier per jt instead of 2).  Fixed-shift softmax (p = exp2(s)).
// P never touches LDS: the swapped QK^T puts P[i][j=16mj+4q+rr] in each lane;
// since vws columns are pre-permuted (phys 8q+4s+r <-> n 16s+4q+r), packing
// {mj=2ks2 rr0..3, mj=2ks2+1 rr0..3} with f2b gives exactly the PV B-operand
// fragment for k-slice ks2 (B k-slot = 8*quad+e).  MFMA sums over k in any
// order, so the j-permutation cancels between P-fragment and V-fragment.
// ---------------------------------------------------------------------------
__global__ __launch_bounds__(256, 4) void attn(
    const u16* __restrict__ qws, const u16* __restrict__ kws,
    const u16* __restrict__ vws, float* __restrict__ out) {
    __shared__ __align__(16) u16 KPb[2][64 * 72];   // K' tiles [64 j][72]
    __shared__ __align__(16) u16 Vtb[2][64 * 72];   // V^T tiles [64 dd][72]

    const int tid  = threadIdx.x;
    const int wave = tid >> 6, lane = tid & 63;
    const int quad = lane >> 4, l16 = lane & 15;
    const int id = blockIdx.x;        // 1024 = (b*8 + qt)*8 + h
    const int h  = id & 7;            // XCD selector
    const int qt = (id >> 3) & 7;
    const int b  = id >> 6;
    const size_t bh = (size_t)b * 8 + h;

    const u16* Q = qws + (bh * 1024 + (size_t)qt * 128) * 64;
    const u16* K = kws + bh * 1024 * 64;
    const u16* V = vws + bh * 64 * 1024;

    const int srow = tid >> 3, sc8 = tid & 7;

    bf16x8 qf[2][2];
#pragma unroll
    for (int ni = 0; ni < 2; ++ni)
#pragma unroll
        for (int ks = 0; ks < 2; ++ks)
            qf[ni][ks] = *(const bf16x8*)(Q + (wave * 32 + ni * 16 + l16) * 64 + ks * 32 + quad * 8);

    f32x4 accO[4][2] = {};
    f32x4 s4[2] = {};

    u16x8 kr0, kr1, vr0, vr1;
    kr0 = *(const u16x8*)(K + (size_t)srow * 64 + sc8 * 8);
    kr1 = *(const u16x8*)(K + (size_t)(srow + 32) * 64 + sc8 * 8);
    vr0 = *(const u16x8*)(V + ((size_t)srow << 10) + sc8 * 8);
    vr1 = *(const u16x8*)(V + ((size_t)(srow + 32) << 10) + sc8 * 8);

    for (int jt = 0; jt < 16; ++jt) {
        u16* KP = KPb[jt & 1];
        u16* Vt = Vtb[jt & 1];
        *(u16x8*)(KP + srow * 72 + sc8 * 8)        = kr0;
        *(u16x8*)(KP + (srow + 32) * 72 + sc8 * 8) = kr1;
        *(u16x8*)(Vt + srow * 72 + sc8 * 8)        = vr0;
        *(u16x8*)(Vt + (srow + 32) * 72 + sc8 * 8) = vr1;
        __syncthreads();                 // writes(jt) -> reads(jt); also
                                         // orders writes(jt+1) after reads(jt-1)

        if (jt < 15) {                   // issue next-tile loads early; they
            const u16* Kn = K + (size_t)(jt + 1) * 64 * 64;   // land across
            const u16* Vn = V + (size_t)(jt + 1) * 64;        // this compute
            kr0 = *(const u16x8*)(Kn + (size_t)srow * 64 + sc8 * 8);
            kr1 = *(const u16x8*)(Kn + (size_t)(srow + 32) * 64 + sc8 * 8);
            vr0 = *(const u16x8*)(Vn + ((size_t)srow << 10) + sc8 * 8);
            vr1 = *(const u16x8*)(Vn + ((size_t)(srow + 32) << 10) + sc8 * 8);
        }

        // ---- QK^T (swapped: A=K rows j, B=Q cols i) ----
        f32x4 accST[4][2] = {};
#pragma unroll
        for (int ks = 0; ks < 2; ++ks) {
            bf16x8 kf[4];
#pragma unroll
            for (int mj = 0; mj < 4; ++mj)
                kf[mj] = *(bf16x8*)(KP + (mj * 16 + l16) * 72 + ks * 32 + quad * 8);
            __builtin_amdgcn_s_setprio(1);
#pragma unroll
            for (int mj = 0; mj < 4; ++mj)
#pragma unroll
                for (int ni = 0; ni < 2; ++ni)
                    accST[mj][ni] = MFMA16(kf[mj], qf[ni][ks], accST[mj][ni]);
            __builtin_amdgcn_s_setprio(0);
        }

        // ---- softmax: p = exp2(s); accumulate row-sum; keep p in accST ----
#pragma unroll
        for (int mj = 0; mj < 4; ++mj)
#pragma unroll
            for (int ni = 0; ni < 2; ++ni) {
                f32x4 p;
#pragma unroll
                for (int rr = 0; rr < 4; ++rr)
                    p[rr] = __builtin_amdgcn_exp2f(accST[mj][ni][rr]);
                s4[ni] += p;
                accST[mj][ni] = p;
            }

        // ---- pack P into PV B-fragments in registers (no LDS) ----
        union pkun { u16x8 u; bf16x8 b; } pfr[2][2];
#pragma unroll
        for (int ks2 = 0; ks2 < 2; ++ks2)
#pragma unroll
            for (int ni = 0; ni < 2; ++ni) {
                u16x8 t;
#pragma unroll
                for (int rr = 0; rr < 4; ++rr) {
                    t[rr]     = f2b_h(accST[2 * ks2][ni][rr]);
                    t[4 + rr] = f2b_h(accST[2 * ks2 + 1][ni][rr]);
                }
                pfr[ks2][ni].u = t;
            }

        // ---- PV (A = V^T rows dd; B = P fragments from registers) ----
#pragma unroll
        for (int ks2 = 0; ks2 < 2; ++ks2) {
            bf16x8 vf[4];
#pragma unroll
            for (int md = 0; md < 4; ++md)
                vf[md] = *(bf16x8*)(Vt + (md * 16 + l16) * 72 + ks2 * 32 + quad * 8);
            __builtin_amdgcn_s_setprio(1);
#pragma unroll
            for (int md = 0; md < 4; ++md)
#pragma unroll
                for (int ni = 0; ni < 2; ++ni)
                    accO[md][ni] = MFMA16(vf[md], pfr[ks2][ni].b, accO[md][ni]);
            __builtin_amdgcn_s_setprio(0);
        }
    }

#pragma unroll
    for (int ni = 0; ni < 2; ++ni) {
        float rs = (s4[ni][0] + s4[ni][1]) + (s4[ni][2] + s4[ni][3]);
        rs += __shfl_xor(rs, 16);
        rs += __shfl_xor(rs, 32);
        float inv = 1.0f / rs;
        int i = qt * 128 + wave * 32 + ni * 16 + l16;
#pragma unroll
        for (int md = 0; md < 4; ++md) {
            f32x4 pk;
#pragma unroll
            for (int rr = 0; rr < 4; ++rr) pk[rr] = accO[md][ni][rr] * inv;
            int dd = md * 16 + quad * 4;
            *(f32x4*)(out + (bh * 1024 + i) * 64 + dd) = pk;
        }
    }
}

// ---------------------------------------------------------------------------
extern "C" void kernel_launch(void* const* d_in, const int* in_sizes, int n_in,
                              void* d_out, int out_size, void* d_ws, size_t ws_size,
                              hipStream_t stream) {
    const float* x  = (const float*)d_in[0];
    const float* Wq = (const float*)d_in[1];
    const float* bq = (const float*)d_in[2];
    const float* Wk = (const float*)d_in[3];
    const float* bk = (const float*)d_in[4];
    const float* Wv = (const float*)d_in[5];
    const float* bv = (const float*)d_in[6];
    const float* rh = (const float*)d_in[7];
    const float* rw = (const float*)d_in[8];
    float* out = (float*)d_out;

    u16* kws = (u16*)d_ws;            // 16 MB bf16 [bh][n][dd]
    u16* vws = kws + 8388608;         // 16 MB bf16 [bh][dd][n-permuted]
    u16* qws = vws + 8388608;         // 16 MB bf16 [bh][n][dd]
    u16* wb  = qws + 8388608;         // 1.5 MB bf16 [3][512][512] (ws: 49.5 MB)
    u16* xT  = (u16*)d_out;           // 16.8 MB bf16 [16][1024][512] in d_out
                                      // (dead before attn overwrites d_out)

    prep<<<1408, 256, 0, stream>>>(x, Wq, Wk, Wv, wb, xT);
    qkv_proj<<<1536, 256, 0, stream>>>(xT, wb, bq, bk, bv, rh, rw, qws, kws, vws);
    attn<<<1024, 256, 0, stream>>>(qws, kws, vws, out);
}